// Round 4
// baseline (100.696 us; speedup 1.0000x reference)
//
#include <hip/hip_runtime.h>

typedef __bf16 bf16x8 __attribute__((ext_vector_type(8)));
typedef float f32x4 __attribute__((ext_vector_type(4)));
typedef unsigned short ushort8 __attribute__((ext_vector_type(8)));
typedef unsigned short ushort4v __attribute__((ext_vector_type(4)));

#define S_LEN 2048
#define DMODEL 1024
#define DHEAD 64
#define QK_SCALE 0.18033688f  /* (1/8) * log2(e) */

static __device__ __forceinline__ unsigned short f2bf(float x) {
  __bf16 h = (__bf16)x;
  return __builtin_bit_cast(unsigned short, h);
}

static __device__ __forceinline__ f32x4 mfma16(bf16x8 a, bf16x8 b, f32x4 c) {
  return __builtin_amdgcn_mfma_f32_16x16x32_bf16(a, b, c, 0, 0, 0);
}

#define GLOAD_LDS(SRC, DST)                                                            \
  __builtin_amdgcn_global_load_lds(                                                    \
      (const __attribute__((address_space(1))) void*)(SRC),                            \
      (__attribute__((address_space(3))) void*)(DST), 16, 0, 0)

// ---- fused prep: wiT [64][1024] bf16  +  wosumT [1024][64] bf16
// wosumT[j][d] = sum_h Wo[h*64+d][j]  (tile(head,16)@Wo == head@Wo_sum; B-frag layout)
__global__ void prep_kernel(const float* __restrict__ wi, const float* __restrict__ Wo,
                            unsigned short* __restrict__ wiT,
                            unsigned short* __restrict__ wosumT) {
  int i = blockIdx.x * 256 + threadIdx.x;  // 131072 total
  if (i < 65536) {
    int n = i >> 10, kk = i & 1023;
    wiT[i] = f2bf(wi[(size_t)kk * DHEAD + n]);
  } else {
    int idx = i - 65536;
    int j = idx & 1023, d = idx >> 10;  // consecutive lanes -> consecutive j (coalesced)
    float s = 0.f;
#pragma unroll
    for (int h = 0; h < 16; ++h) s += Wo[(size_t)(h * 64 + d) * 1024 + j];
    wosumT[(size_t)j * 64 + d] = f2bf(s);
  }
}

// ---- projections v4: DRAM-page-friendly streaming.
// r0-r3 post-mortem: 4 different schedules all ~41-44us at 1.3 TB/s with every pipe
// idle. Invariant across all four: A-reads advanced each of 24K concurrent row-streams
// by only 128B per access (4KB stride between streams) -> HBM row-activate per 128B ->
// ~1/5 DRAM efficiency. THE ACCESS PATTERN, not the schedule, was the limiter.
// Fix: 4 super-stages of 1KB-PER-ROW contiguous DMAs (16 per stage, each a single
// fully-sequential 1KB fetch of one row -> row-activate amortized 8x). B (wiT 128KB,
// L2-resident, pattern-insensitive) leaves LDS: per-lane register loads from L2.
// LDS = depth-2 x 16KB A-ring (5 blocks/CU); swizzle folded into per-lane DMA SOURCE
// (16B-unit XOR within 128B groups; dest linear per m104/m173); counted vmcnt(16).
__global__ __launch_bounds__(64) void proj_kernel(
    const float* __restrict__ q, const float* __restrict__ k, const float* __restrict__ v,
    const unsigned short* __restrict__ wiT,
    float* __restrict__ qp32, unsigned short* __restrict__ qp_bf,
    unsigned short* __restrict__ kp_bf, unsigned short* __restrict__ vpT) {
  int bx = blockIdx.x;       // 1536 blocks: 512 per tensor
  int ten = bx >> 9;         // 0:q 1:k 2:v
  int m0 = (bx & 511) << 4;  // 16-row strip
  const float* x = (ten == 0) ? q : ((ten == 1) ? k : v);
  int lane = threadIdx.x;
  int l15 = lane & 15, lg = lane >> 4;

  __shared__ __align__(16) char As[2][16384];  // [buf][row 0..15][1024B], src-side swizzle

  const char* xb = (const char*)x + (size_t)m0 * 4096;
  int hi = (lane & 56) << 4;  // per-lane coarse 16B-unit offset (bits 3..5 of lane)
  int lo = lane & 7;

  // stage ss: rows 0..15, each DMA = one contiguous 1KB of row r at k-bytes [ss*1024..)
  auto ISSUE = [&](int ss) {
    char* dst = As[ss & 1];
    const char* s0 = xb + (size_t)ss * 1024;
#pragma unroll
    for (int r = 0; r < 16; ++r) {
      const char* src = s0 + (size_t)r * 4096 + (hi | (((lo ^ (r & 7))) << 4));
      GLOAD_LDS(src, dst + r * 1024);
    }
  };

  f32x4 acc[4] = {};
  int sw = (l15 & 7) << 4;

  // stage ss: 8 sub-steps of K=32; A from LDS (swizzled), B straight from L2.
  auto COMP = [&](int ss) {
    const char* Ab = As[ss & 1] + l15 * 1024;
    const unsigned short* bp0 = wiT + (size_t)l15 * 1024 + ss * 256 + lg * 8;
#pragma unroll
    for (int s = 0; s < 8; ++s) {
      int off = s * 128 + lg * 32;
      f32x4 a0 = *(const f32x4*)(Ab + (off ^ sw));
      f32x4 a1 = *(const f32x4*)(Ab + ((off + 16) ^ sw));
      bf16x8 af;
      af[0] = (__bf16)a0[0]; af[1] = (__bf16)a0[1]; af[2] = (__bf16)a0[2]; af[3] = (__bf16)a0[3];
      af[4] = (__bf16)a1[0]; af[5] = (__bf16)a1[1]; af[6] = (__bf16)a1[2]; af[7] = (__bf16)a1[3];
      const unsigned short* bp = bp0 + s * 32;
#pragma unroll
      for (int t = 0; t < 4; ++t) {
        bf16x8 bfr = *(const bf16x8*)(bp + t * 16 * 1024);
        acc[t] = mfma16(af, bfr, acc[t]);
      }
    }
  };

  ISSUE(0);
  ISSUE(1);
  asm volatile("s_waitcnt vmcnt(16)" ::: "memory");  // stage 0 landed (stage 1 in flight)
  __builtin_amdgcn_sched_barrier(0);
  COMP(0);
  __builtin_amdgcn_sched_barrier(0);
  asm volatile("s_waitcnt lgkmcnt(0)" ::: "memory");  // buf0 reads done before rewrite
  __builtin_amdgcn_sched_barrier(0);
  ISSUE(2);
  asm volatile("s_waitcnt vmcnt(16)" ::: "memory");  // stage 1 landed (+drains stray B loads)
  __builtin_amdgcn_sched_barrier(0);
  COMP(1);
  __builtin_amdgcn_sched_barrier(0);
  asm volatile("s_waitcnt lgkmcnt(0)" ::: "memory");
  __builtin_amdgcn_sched_barrier(0);
  ISSUE(3);
  asm volatile("s_waitcnt vmcnt(16)" ::: "memory");  // stage 2 landed
  __builtin_amdgcn_sched_barrier(0);
  COMP(2);
  __builtin_amdgcn_sched_barrier(0);
  asm volatile("s_waitcnt vmcnt(0)" ::: "memory");   // stage 3 landed
  __builtin_amdgcn_sched_barrier(0);
  COMP(3);

  if (ten == 2) {
    // transpose 16 kv-rows x 64 d through LDS (alias the A ring), store vpT [b][dh][kv]
    unsigned short(*vt)[72] = (unsigned short(*)[72]) & As[0][0];
#pragma unroll
    for (int t = 0; t < 4; ++t)
#pragma unroll
      for (int r = 0; r < 4; ++r)
        vt[lg * 4 + r][t * 16 + l15] = f2bf(acc[t][r]);
    __syncthreads();  // single-wave block: cheap
    int bq = m0 >> 11, kvb = m0 & 2047;
    unsigned short* dst = vpT + (size_t)bq * (DHEAD * S_LEN) + (size_t)lane * S_LEN + kvb;
    ushort8 o0, o1;
#pragma unroll
    for (int j = 0; j < 8; ++j) {
      o0[j] = vt[j][lane];
      o1[j] = vt[8 + j][lane];
    }
    *(ushort8*)dst = o0;
    *(ushort8*)(dst + 8) = o1;
  } else {
#pragma unroll
    for (int t = 0; t < 4; ++t) {
      int gc = t * 16 + l15;
#pragma unroll
      for (int r = 0; r < 4; ++r) {
        size_t idx = (size_t)(m0 + lg * 4 + r) * DHEAD + gc;
        float val = acc[t][r];
        if (ten == 0) {
          qp32[idx] = val;
          qp_bf[idx] = f2bf(val * QK_SCALE);
        } else {
          kp_bf[idx] = f2bf(val);
        }
      }
    }
  }
}

// ---- flash attention, fixed-max softmax, 4-way KV split per block
// NO in-loop barriers: P_lds[w] is written AND read by wave w only -- the
// compiler's lgkmcnt dependency wait orders the round-trip. Waves fully
// decoupled until the final cross-wave combine barrier.
__global__ __launch_bounds__(256) void attn_kernel(
    const unsigned short* __restrict__ qp_bf, const unsigned short* __restrict__ kp_bf,
    const unsigned short* __restrict__ vpT, const float* __restrict__ qp32,
    unsigned short* __restrict__ head_bf) {
  int bx = blockIdx.x;
  int b = bx >> 7;
  int q0 = (bx & 127) << 4;
  int tid = threadIdx.x, lane = tid & 63, w = tid >> 6;
  int l15 = lane & 15, lg = lane >> 4;

  __shared__ __align__(16) unsigned short P_lds[4][16][72];  // per-wave P round-trip
  __shared__ __align__(16) float part[4][16][64];            // per-wave PV partials
  __shared__ float lsum_lds[4][16];                          // per-wave denom partials

  size_t base = (size_t)b * (S_LEN * DHEAD);
  const unsigned short* qrow_p = qp_bf + base + (size_t)(q0 + l15) * DHEAD + lg * 8;
  bf16x8 qf0 = *(const bf16x8*)qrow_p;  // B-frag: n=q, k=dh
  bf16x8 qf1 = *(const bf16x8*)(qrow_p + 32);

  const unsigned short* vbase = vpT + (size_t)b * (DHEAD * S_LEN);

  f32x4 oacc[4] = {};
  float lsum_p = 0.f;  // per-lane partial denom for q = q0 + l15

  for (int it = 0; it < 8; ++it) {
    int kv0 = w * 512 + it * 64;
    const unsigned short* kt = kp_bf + base + (size_t)kv0 * DHEAD;
    f32x4 sc[4];
    // swapped QK^T: mfma(K,Q) -> lane holds S(q = q0+l15, kv = kv0 + sub*16 + lg*4 + r)
#pragma unroll
    for (int sub = 0; sub < 4; ++sub) {
      bf16x8 kf0 = *(const bf16x8*)(kt + (size_t)(sub * 16 + l15) * DHEAD + lg * 8);
      bf16x8 kf1 = *(const bf16x8*)(kt + (size_t)(sub * 16 + l15) * DHEAD + 32 + lg * 8);
      f32x4 z = {};
      z = mfma16(kf0, qf0, z);
      sc[sub] = mfma16(kf1, qf1, z);
    }
    // fixed-max softmax: p = exp2(s); denom deferred (per-lane partial, q is lane-local)
#pragma unroll
    for (int sub = 0; sub < 4; ++sub) {
      ushort4v pw;
#pragma unroll
      for (int r = 0; r < 4; ++r) {
        float p = exp2f(sc[sub][r]);
        lsum_p += p;
        pw[r] = f2bf(p);
      }
      *(ushort4v*)&P_lds[w][l15][sub * 16 + lg * 4] = pw;  // row-local packed b64 write
    }
    // PV: A-frag = P (m=q, k=kv), B-frag = V^T (n=dh, k=kv), same k-order both sides
#pragma unroll
    for (int c = 0; c < 2; ++c) {
      bf16x8 pf = *(const bf16x8*)&P_lds[w][l15][c * 32 + lg * 8];  // same-wave read
      const unsigned short* vt2 = vbase + kv0 + c * 32 + lg * 8;
#pragma unroll
      for (int t = 0; t < 4; ++t) {
        bf16x8 vf = *(const bf16x8*)(vt2 + (size_t)(t * 16 + l15) * S_LEN);
        oacc[t] = mfma16(pf, vf, oacc[t]);
      }
    }
  }

  // finish denom: reduce across the 4 lg groups (same l15 = same q)
  lsum_p += __shfl_xor(lsum_p, 16);
  lsum_p += __shfl_xor(lsum_p, 32);

  // write per-wave partials (fixed-max => partials combine by plain addition)
#pragma unroll
  for (int t = 0; t < 4; ++t)
#pragma unroll
    for (int r = 0; r < 4; ++r)
      part[w][lg * 4 + r][t * 16 + l15] = oacc[t][r];
  if (lane < 16) lsum_lds[w][l15] = lsum_p;
  __syncthreads();  // cross-wave combine barrier (stays)

  {
    int qr = tid >> 4, d0 = (tid & 15) << 2;
    f32x4 s = *(const f32x4*)&part[0][qr][d0];
    s += *(const f32x4*)&part[1][qr][d0];
    s += *(const f32x4*)&part[2][qr][d0];
    s += *(const f32x4*)&part[3][qr][d0];
    float l = lsum_lds[0][qr] + lsum_lds[1][qr] + lsum_lds[2][qr] + lsum_lds[3][qr];
    float inv = 1.0f / l;
    size_t idx = base + (size_t)(q0 + qr) * DHEAD + d0;
    f32x4 qv = *(const f32x4*)(qp32 + idx);
    f32x4 res = qv + s * inv;
    ushort4v hb;
#pragma unroll
    for (int j = 0; j < 4; ++j) hb[j] = f2bf(res[j]);
    *(ushort4v*)(head_bf + idx) = hb;  // bf16 head: residual + normalized PV
  }
}

// ---- out = head_bf[8192x64] @ wosumT^T [64x1024] + bo, via MFMA (K=64)
// Same fragment conventions as proj (A rows = m, B rows = n, verified C-layout).
__global__ __launch_bounds__(256) void out_kernel(
    const unsigned short* __restrict__ head_bf, const unsigned short* __restrict__ wosumT,
    const float* __restrict__ bo, float* __restrict__ out) {
  int bx = blockIdx.x;
  int m0 = (bx >> 3) << 6;  // 128 row-blocks of 64
  int c0 = (bx & 7) << 7;   // 8 col-blocks of 128
  int tid = threadIdx.x, lane = tid & 63, w = tid >> 6;
  int l15 = lane & 15, lg = lane >> 4;

  const unsigned short* ap = head_bf + (size_t)(m0 + w * 16 + l15) * DHEAD + lg * 8;
  bf16x8 af0 = *(const bf16x8*)ap;         // k = lg*8..+8
  bf16x8 af1 = *(const bf16x8*)(ap + 32);  // k = 32+lg*8..+8

  f32x4 acc[8] = {};
#pragma unroll
  for (int t = 0; t < 8; ++t) {
    const unsigned short* bp = wosumT + (size_t)(c0 + t * 16 + l15) * DHEAD + lg * 8;
    bf16x8 b0 = *(const bf16x8*)bp;
    bf16x8 b1 = *(const bf16x8*)(bp + 32);
    acc[t] = mfma16(af0, b0, acc[t]);
    acc[t] = mfma16(af1, b1, acc[t]);
  }
#pragma unroll
  for (int t = 0; t < 8; ++t) {
    int col = c0 + t * 16 + l15;
    float bias = bo[col];
#pragma unroll
    for (int r = 0; r < 4; ++r) {
      int row = m0 + w * 16 + lg * 4 + r;
      out[(size_t)row * 1024 + col] = acc[t][r] + bias;
    }
  }
}

extern "C" void kernel_launch(void* const* d_in, const int* in_sizes, int n_in,
                              void* d_out, int out_size, void* d_ws, size_t ws_size,
                              hipStream_t stream) {
  (void)in_sizes; (void)n_in; (void)out_size; (void)ws_size;
  const float* v = (const float*)d_in[0];
  const float* k = (const float*)d_in[1];
  const float* q = (const float*)d_in[2];
  const float* wi = (const float*)d_in[3];
  const float* Wo = (const float*)d_in[4];
  const float* bo = (const float*)d_in[5];
  float* out = (float*)d_out;
  char* ws = (char*)d_ws;

  float* qp32 = (float*)(ws + 0);                                // 2 MB
  unsigned short* head_bf = (unsigned short*)(ws + (2u << 20));  // 1 MB
  unsigned short* qp_bf = (unsigned short*)(ws + (4u << 20));    // 1 MB
  unsigned short* kp_bf = (unsigned short*)(ws + (5u << 20));    // 1 MB
  unsigned short* vpT = (unsigned short*)(ws + (6u << 20));      // 1 MB  [b][dh][kv]
  unsigned short* wiT = (unsigned short*)(ws + (7u << 20));      // 128 KB
  unsigned short* wosumT = (unsigned short*)(ws + (7u << 20) + (512u << 10));  // 128 KB

  prep_kernel<<<512, 256, 0, stream>>>(wi, Wo, wiT, wosumT);
  proj_kernel<<<1536, 64, 0, stream>>>(q, k, v, wiT, qp32, qp_bf, kp_bf, vpT);
  attn_kernel<<<512, 256, 0, stream>>>(qp_bf, kp_bf, vpT, qp32, head_bf);
  out_kernel<<<1024, 256, 0, stream>>>(head_bf, wosumT, bo, out);
}

// Round 5
// 85.557 us; speedup vs baseline: 1.1769x; 1.1769x over previous
//
#include <hip/hip_runtime.h>

typedef __bf16 bf16x8 __attribute__((ext_vector_type(8)));
typedef float f32x4 __attribute__((ext_vector_type(4)));
typedef unsigned short ushort8 __attribute__((ext_vector_type(8)));
typedef unsigned short ushort4v __attribute__((ext_vector_type(4)));

#define S_LEN 2048
#define DMODEL 1024
#define DHEAD 64
#define QK_SCALE 0.18033688f  /* (1/8) * log2(e) */

static __device__ __forceinline__ unsigned short f2bf(float x) {
  __bf16 h = (__bf16)x;
  return __builtin_bit_cast(unsigned short, h);
}

static __device__ __forceinline__ f32x4 mfma16(bf16x8 a, bf16x8 b, f32x4 c) {
  return __builtin_amdgcn_mfma_f32_16x16x32_bf16(a, b, c, 0, 0, 0);
}

// ---- fused prep: wiT [64][1024] bf16  +  wosumT [1024][64] bf16
// wosumT[j][d] = sum_h Wo[h*64+d][j]  (tile(head,16)@Wo == head@Wo_sum; B-frag layout)
__global__ void prep_kernel(const float* __restrict__ wi, const float* __restrict__ Wo,
                            unsigned short* __restrict__ wiT,
                            unsigned short* __restrict__ wosumT) {
  int i = blockIdx.x * 256 + threadIdx.x;  // 131072 total
  if (i < 65536) {
    int n = i >> 10, kk = i & 1023;
    wiT[i] = f2bf(wi[(size_t)kk * DHEAD + n]);
  } else {
    int idx = i - 65536;
    int j = idx & 1023, d = idx >> 10;  // consecutive lanes -> consecutive j (coalesced)
    float s = 0.f;
#pragma unroll
    for (int h = 0; h < 16; ++h) s += Wo[(size_t)(h * 64 + d) * 1024 + j];
    wosumT[(size_t)j * 64 + d] = f2bf(s);
  }
}

// ---- projections v5: memcpy-shaped streaming.
// r0-r4 post-mortem: every schedule stuck at 1.0-1.4 TB/s. Invariant: all walked
// 16-32 rows in parallel at 128B-1KB granularity with 4KB hops (~24K fragmented
// streams). The one measured-fast pattern on this data (fillBuffer 6.7 TB/s @ 8%
// occupancy) is a dense linear per-block front. v5 decouples read order from
// K-loop order:
//   Phase A: block scans its CONTIGUOUS 64KB (16 rows fp32) exactly like memcpy --
//     256 thr x 16B = one 4KB row per step, 16 steps, all 16 loads/thread issued
//     up-front (64 VGPRs, independent). Convert->bf16 -> swizzled LDS [16][1024].
//   Phase B: 1 barrier, then pure MFMA: wave w owns cols w*16..+16; A-frag is ONE
//     ds_read_b128 (already bf16), B streamed from L2-resident wiT. No staging,
//     no inline asm, nothing for the scheduler to break.
// LDS 32KB -> 4-5 blocks/CU (16-20 waves of streaming TLP).
__global__ __launch_bounds__(256, 4) void proj_kernel(
    const float* __restrict__ q, const float* __restrict__ k, const float* __restrict__ v,
    const unsigned short* __restrict__ wiT,
    float* __restrict__ qp32, unsigned short* __restrict__ qp_bf,
    unsigned short* __restrict__ kp_bf, unsigned short* __restrict__ vpT) {
  int bx = blockIdx.x;       // 1536 blocks: 512 per tensor
  int ten = bx >> 9;         // 0:q 1:k 2:v
  int m0 = (bx & 511) << 4;  // 16-row strip
  const float* x = (ten == 0) ? q : ((ten == 1) ? k : v);
  int tid = threadIdx.x, lane = tid & 63, w = tid >> 6;
  int l15 = lane & 15, lg = lane >> 4;

  __shared__ __align__(16) unsigned short Abf[16][1024];  // 32KB, row-XOR-swizzled

  // ---- Phase A: linear 64KB scan -> bf16 LDS
  const char* src = (const char*)x + (size_t)m0 * 4096 + tid * 16;
  f32x4 ld[16];
#pragma unroll
  for (int s = 0; s < 16; ++s) ld[s] = *(const f32x4*)(src + (size_t)s * 4096);
#pragma unroll
  for (int s = 0; s < 16; ++s) {
    ushort4v hv;
    hv[0] = f2bf(ld[s][0]);
    hv[1] = f2bf(ld[s][1]);
    hv[2] = f2bf(ld[s][2]);
    hv[3] = f2bf(ld[s][3]);
    // row s, byte offset (tid*8) ^ ((s&7)<<4): XOR bits 4-6, 8B chunks stay intact
    *(ushort4v*)((char*)&Abf[s][0] + ((tid * 8) ^ ((s & 7) << 4))) = hv;
  }
  __syncthreads();

  // ---- Phase B: out[m=0..15][n=w*16..+16] over K=1024
  f32x4 acc = {};
  const char* Arow = (const char*)&Abf[l15][0];  // m = l15
  const unsigned short* bcol = wiT + (size_t)(w * 16 + l15) * 1024 + lg * 8;  // n = w*16+l15
  int swz = (l15 & 7) << 4;
#pragma unroll
  for (int s = 0; s < 32; ++s) {
    bf16x8 af = *(const bf16x8*)(Arow + ((s * 64 + lg * 16) ^ swz));
    bf16x8 bfr = *(const bf16x8*)(bcol + s * 32);
    acc = mfma16(af, bfr, acc);
  }

  // ---- epilogue: C row = m0 + lg*4 + r, col = w*16 + l15 (verified D-layout)
  if (ten == 2) {
    __syncthreads();  // all waves done reading Abf before reuse
    unsigned short(*vt)[68] = (unsigned short(*)[68]) & Abf[0][0];  // [kv 16][d 64+pad]
#pragma unroll
    for (int r = 0; r < 4; ++r) vt[lg * 4 + r][w * 16 + l15] = f2bf(acc[r]);
    __syncthreads();
    int d = tid >> 2, c4 = (tid & 3) << 2;
    ushort4v o;
#pragma unroll
    for (int j = 0; j < 4; ++j) o[j] = vt[c4 + j][d];
    int bq = m0 >> 11, kvb = m0 & 2047;
    *(ushort4v*)(vpT + (size_t)bq * (DHEAD * S_LEN) + (size_t)d * S_LEN + kvb + c4) = o;
  } else {
#pragma unroll
    for (int r = 0; r < 4; ++r) {
      size_t idx = (size_t)(m0 + lg * 4 + r) * DHEAD + (w * 16 + l15);
      float val = acc[r];
      if (ten == 0) {
        qp32[idx] = val;
        qp_bf[idx] = f2bf(val * QK_SCALE);
      } else {
        kp_bf[idx] = f2bf(val);
      }
    }
  }
}

// ---- flash attention, fixed-max softmax, 4-way KV split per block
// NO in-loop barriers: P_lds[w] is written AND read by wave w only -- the
// compiler's lgkmcnt dependency wait orders the round-trip. Waves fully
// decoupled until the final cross-wave combine barrier.
__global__ __launch_bounds__(256) void attn_kernel(
    const unsigned short* __restrict__ qp_bf, const unsigned short* __restrict__ kp_bf,
    const unsigned short* __restrict__ vpT, const float* __restrict__ qp32,
    unsigned short* __restrict__ head_bf) {
  int bx = blockIdx.x;
  int b = bx >> 7;
  int q0 = (bx & 127) << 4;
  int tid = threadIdx.x, lane = tid & 63, w = tid >> 6;
  int l15 = lane & 15, lg = lane >> 4;

  __shared__ __align__(16) unsigned short P_lds[4][16][72];  // per-wave P round-trip
  __shared__ __align__(16) float part[4][16][64];            // per-wave PV partials
  __shared__ float lsum_lds[4][16];                          // per-wave denom partials

  size_t base = (size_t)b * (S_LEN * DHEAD);
  const unsigned short* qrow_p = qp_bf + base + (size_t)(q0 + l15) * DHEAD + lg * 8;
  bf16x8 qf0 = *(const bf16x8*)qrow_p;  // B-frag: n=q, k=dh
  bf16x8 qf1 = *(const bf16x8*)(qrow_p + 32);

  const unsigned short* vbase = vpT + (size_t)b * (DHEAD * S_LEN);

  f32x4 oacc[4] = {};
  float lsum_p = 0.f;  // per-lane partial denom for q = q0 + l15

  for (int it = 0; it < 8; ++it) {
    int kv0 = w * 512 + it * 64;
    const unsigned short* kt = kp_bf + base + (size_t)kv0 * DHEAD;
    f32x4 sc[4];
    // swapped QK^T: mfma(K,Q) -> lane holds S(q = q0+l15, kv = kv0 + sub*16 + lg*4 + r)
#pragma unroll
    for (int sub = 0; sub < 4; ++sub) {
      bf16x8 kf0 = *(const bf16x8*)(kt + (size_t)(sub * 16 + l15) * DHEAD + lg * 8);
      bf16x8 kf1 = *(const bf16x8*)(kt + (size_t)(sub * 16 + l15) * DHEAD + 32 + lg * 8);
      f32x4 z = {};
      z = mfma16(kf0, qf0, z);
      sc[sub] = mfma16(kf1, qf1, z);
    }
    // fixed-max softmax: p = exp2(s); denom deferred (per-lane partial, q is lane-local)
#pragma unroll
    for (int sub = 0; sub < 4; ++sub) {
      ushort4v pw;
#pragma unroll
      for (int r = 0; r < 4; ++r) {
        float p = exp2f(sc[sub][r]);
        lsum_p += p;
        pw[r] = f2bf(p);
      }
      *(ushort4v*)&P_lds[w][l15][sub * 16 + lg * 4] = pw;  // row-local packed b64 write
    }
    // PV: A-frag = P (m=q, k=kv), B-frag = V^T (n=dh, k=kv), same k-order both sides
#pragma unroll
    for (int c = 0; c < 2; ++c) {
      bf16x8 pf = *(const bf16x8*)&P_lds[w][l15][c * 32 + lg * 8];  // same-wave read
      const unsigned short* vt2 = vbase + kv0 + c * 32 + lg * 8;
#pragma unroll
      for (int t = 0; t < 4; ++t) {
        bf16x8 vf = *(const bf16x8*)(vt2 + (size_t)(t * 16 + l15) * S_LEN);
        oacc[t] = mfma16(pf, vf, oacc[t]);
      }
    }
  }

  // finish denom: reduce across the 4 lg groups (same l15 = same q)
  lsum_p += __shfl_xor(lsum_p, 16);
  lsum_p += __shfl_xor(lsum_p, 32);

  // write per-wave partials (fixed-max => partials combine by plain addition)
#pragma unroll
  for (int t = 0; t < 4; ++t)
#pragma unroll
    for (int r = 0; r < 4; ++r)
      part[w][lg * 4 + r][t * 16 + l15] = oacc[t][r];
  if (lane < 16) lsum_lds[w][l15] = lsum_p;
  __syncthreads();  // cross-wave combine barrier (stays)

  {
    int qr = tid >> 4, d0 = (tid & 15) << 2;
    f32x4 s = *(const f32x4*)&part[0][qr][d0];
    s += *(const f32x4*)&part[1][qr][d0];
    s += *(const f32x4*)&part[2][qr][d0];
    s += *(const f32x4*)&part[3][qr][d0];
    float l = lsum_lds[0][qr] + lsum_lds[1][qr] + lsum_lds[2][qr] + lsum_lds[3][qr];
    float inv = 1.0f / l;
    size_t idx = base + (size_t)(q0 + qr) * DHEAD + d0;
    f32x4 qv = *(const f32x4*)(qp32 + idx);
    f32x4 res = qv + s * inv;
    ushort4v hb;
#pragma unroll
    for (int j = 0; j < 4; ++j) hb[j] = f2bf(res[j]);
    *(ushort4v*)(head_bf + idx) = hb;  // bf16 head: residual + normalized PV
  }
}

// ---- out = head_bf[8192x64] @ wosumT^T [64x1024] + bo, via MFMA (K=64)
// Same fragment conventions as proj (A rows = m, B rows = n, verified C-layout).
__global__ __launch_bounds__(256) void out_kernel(
    const unsigned short* __restrict__ head_bf, const unsigned short* __restrict__ wosumT,
    const float* __restrict__ bo, float* __restrict__ out) {
  int bx = blockIdx.x;
  int m0 = (bx >> 3) << 6;  // 128 row-blocks of 64
  int c0 = (bx & 7) << 7;   // 8 col-blocks of 128
  int tid = threadIdx.x, lane = tid & 63, w = tid >> 6;
  int l15 = lane & 15, lg = lane >> 4;

  const unsigned short* ap = head_bf + (size_t)(m0 + w * 16 + l15) * DHEAD + lg * 8;
  bf16x8 af0 = *(const bf16x8*)ap;         // k = lg*8..+8
  bf16x8 af1 = *(const bf16x8*)(ap + 32);  // k = 32+lg*8..+8

  f32x4 acc[8] = {};
#pragma unroll
  for (int t = 0; t < 8; ++t) {
    const unsigned short* bp = wosumT + (size_t)(c0 + t * 16 + l15) * DHEAD + lg * 8;
    bf16x8 b0 = *(const bf16x8*)bp;
    bf16x8 b1 = *(const bf16x8*)(bp + 32);
    acc[t] = mfma16(af0, b0, acc[t]);
    acc[t] = mfma16(af1, b1, acc[t]);
  }
#pragma unroll
  for (int t = 0; t < 8; ++t) {
    int col = c0 + t * 16 + l15;
    float bias = bo[col];
#pragma unroll
    for (int r = 0; r < 4; ++r) {
      int row = m0 + w * 16 + lg * 4 + r;
      out[(size_t)row * 1024 + col] = acc[t][r] + bias;
    }
  }
}

extern "C" void kernel_launch(void* const* d_in, const int* in_sizes, int n_in,
                              void* d_out, int out_size, void* d_ws, size_t ws_size,
                              hipStream_t stream) {
  (void)in_sizes; (void)n_in; (void)out_size; (void)ws_size;
  const float* v = (const float*)d_in[0];
  const float* k = (const float*)d_in[1];
  const float* q = (const float*)d_in[2];
  const float* wi = (const float*)d_in[3];
  const float* Wo = (const float*)d_in[4];
  const float* bo = (const float*)d_in[5];
  float* out = (float*)d_out;
  char* ws = (char*)d_ws;

  float* qp32 = (float*)(ws + 0);                                // 2 MB
  unsigned short* head_bf = (unsigned short*)(ws + (2u << 20));  // 1 MB
  unsigned short* qp_bf = (unsigned short*)(ws + (4u << 20));    // 1 MB
  unsigned short* kp_bf = (unsigned short*)(ws + (5u << 20));    // 1 MB
  unsigned short* vpT = (unsigned short*)(ws + (6u << 20));      // 1 MB  [b][dh][kv]
  unsigned short* wiT = (unsigned short*)(ws + (7u << 20));      // 128 KB
  unsigned short* wosumT = (unsigned short*)(ws + (7u << 20) + (512u << 10));  // 128 KB

  prep_kernel<<<512, 256, 0, stream>>>(wi, Wo, wiT, wosumT);
  proj_kernel<<<1536, 256, 0, stream>>>(q, k, v, wiT, qp32, qp_bf, kp_bf, vpT);
  attn_kernel<<<512, 256, 0, stream>>>(qp_bf, kp_bf, vpT, qp32, head_bf);
  out_kernel<<<1024, 256, 0, stream>>>(head_bf, wosumT, bo, out);
}